// Round 1
// 53.556 us; speedup vs baseline: 1.0157x; 1.0157x over previous
//
#include <hip/hip_runtime.h>

// ball_query(radius=3.4, nsample=5) — 16 LANES PER QUERY (4 queries/wave).
// B=8, N=4096, D=3. Output [B, N, 5] int32.
//
// Round 7: the kernel's duration is the critical path of the WORST wave --
// a query far from the origin that must scan deep (up to all 4096 points).
// Previous cold path scanned 16 candidates/iter/query with all 4 groups
// looping together: ~255 dependent iterations for a full scan (~14 us).
// Now the cold path iterates over unfinished groups and uses ALL 64 lanes
// on one query, unrolled x2 = 128 candidates/iteration (both chunks' loads
// issued up front to overlap L2 latency). Full scan: ~32 iterations (~8x
// fewer latency-bound steps). Hot path (first 16 candidates, covers ~96%
// of queries) is unchanged.
//
// d2 must match the numpy reference at the r2 boundary:
//   d2 = (sq_q + sq_k) - 2*dot, sq/dot separately-rounded f32 (no fma) —
//   file-scope fp contract(off). Self-distance is exactly 0 with this
//   expression, so every query has >=1 hit (first-hit fill always valid).

#pragma clang fp contract(off)

#define BQ_N 4096
#define BQ_B 8
#define BQ_NS 5

__global__ __launch_bounds__(1024) void ball_query_kernel(
    const float* __restrict__ x, int* __restrict__ out, float r2) {
  const int wid = (blockIdx.x * 1024 + threadIdx.x) >> 6;  // global wave
  const int lane = threadIdx.x & 63;
  const int group = lane >> 4;   // 0..3 — which query this lane serves
  const int sub = lane & 15;     // 0..15 — candidate offset within chunk

  const int qidx = wid * 4 + group;   // 4 consecutive queries per wave
  const int b = qidx >> 12;           // / 4096 (wave-uniform: qidx aligned 4)
  const int q = qidx & (BQ_N - 1);    // % 4096

  const float* xb = x + (size_t)b * BQ_N * 3;

  // Query coords + first 16 candidates (replicated across groups).
  const float qx = xb[q * 3 + 0];
  const float qy = xb[q * 3 + 1];
  const float qz = xb[q * 3 + 2];
  const float kx0 = xb[sub * 3 + 0];
  const float ky0 = xb[sub * 3 + 1];
  const float kz0 = xb[sub * 3 + 2];

  const float sq_q = (qx * qx + qy * qy) + qz * qz;
  const float sqk0 = (kx0 * kx0 + ky0 * ky0) + kz0 * kz0;
  const float dot0 = (qx * kx0 + qy * ky0) + qz * kz0;
  const float d20 = (sq_q + sqk0) - 2.0f * dot0;

  const int base = qidx * BQ_NS;
  const unsigned sublow = (1u << sub) - 1u;  // bits below sub within group

  const unsigned long long m1 = __ballot(d20 < r2);
  const unsigned mg1 = (unsigned)(m1 >> (group * 16)) & 0xFFFFu;
  if (d20 < r2) {
    const int rank = __popc(mg1 & sublow);
    if (rank < BQ_NS) out[base + rank] = sub;
  }
  int cnt = __popc(mg1);  // group-uniform

  if (__any(cnt < BQ_NS)) {  // rare cold path (~4% of waves)
    const int first0 = (mg1 != 0u) ? (__ffs(mg1) - 1) : -1;
    const unsigned long long lanelow = (1ull << lane) - 1ull;

    // Serially finish each cold group with the FULL wave (64 lanes/query,
    // 128 candidates/iteration). Group state is broadcast from lane g*16.
    for (int g = 0; g < 4; ++g) {
      int cntg = __shfl(cnt, g * 16);
      if (cntg >= BQ_NS) continue;
      int firstg = __shfl(first0, g * 16);
      const float gqx = __shfl(qx, g * 16);
      const float gqy = __shfl(qy, g * 16);
      const float gqz = __shfl(qz, g * 16);
      const float gsq = __shfl(sq_q, g * 16);
      const int gbase = (wid * 4 + g) * BQ_NS;

      for (int k0 = 16; k0 < BQ_N && cntg < BQ_NS; k0 += 128) {
        const int ka = k0 + lane;
        const int kb = ka + 64;
        const int kca = (ka < BQ_N) ? ka : (BQ_N - 1);  // clamp (mask below)
        const int kcb = (kb < BQ_N) ? kb : (BQ_N - 1);
        // Issue both chunks' loads up front (independent -> overlap L2 lat).
        const float ax = xb[kca * 3 + 0];
        const float ay = xb[kca * 3 + 1];
        const float az = xb[kca * 3 + 2];
        const float bx = xb[kcb * 3 + 0];
        const float by = xb[kcb * 3 + 1];
        const float bz = xb[kcb * 3 + 2];

        const float sqa = (ax * ax + ay * ay) + az * az;
        const float dota = (gqx * ax + gqy * ay) + gqz * az;
        const float d2a = (gsq + sqa) - 2.0f * dota;
        const float sqb = (bx * bx + by * by) + bz * bz;
        const float dotb = (gqx * bx + gqy * by) + gqz * bz;
        const float d2b = (gsq + sqb) - 2.0f * dotb;

        const bool ha = (d2a < r2) && (ka < BQ_N);
        const bool hb = (d2b < r2) && (kb < BQ_N);
        const unsigned long long ma = __ballot(ha);
        const unsigned long long mb = __ballot(hb);

        // Chunk A (scan order = lane order).
        if (ha && cntg < BQ_NS) {
          const int rank = cntg + __popcll(ma & lanelow);
          if (rank < BQ_NS) out[gbase + rank] = ka;
        }
        const int cnta = cntg + __popcll(ma);
        // Chunk B continues from cnta.
        if (hb && cnta < BQ_NS) {
          const int rank = cnta + __popcll(mb & lanelow);
          if (rank < BQ_NS) out[gbase + rank] = kb;
        }
        if (firstg < 0) {
          if (ma)      firstg = k0 + __builtin_ctzll(ma);
          else if (mb) firstg = k0 + 64 + __builtin_ctzll(mb);
        }
        cntg = cnta + __popcll(mb);
      }

      // Unfilled slots hold the FIRST found index (cnt>=1 always: self-hit).
      if (lane == 0 && cntg < BQ_NS) {
        const int s = (cntg < 1) ? 1 : cntg;
        for (int j = s; j < BQ_NS; ++j) out[gbase + j] = firstg;
      }
    }
  }
}

extern "C" void kernel_launch(void* const* d_in, const int* in_sizes, int n_in,
                              void* d_out, int out_size, void* d_ws, size_t ws_size,
                              hipStream_t stream) {
  const float* x = (const float*)d_in[0];
  int* out = (int*)d_out;
  const float r2 = 3.4f * 3.4f;  // 11.56

  const int total_waves = (BQ_B * BQ_N) / 4;  // 4 queries per wave -> 8192
  const int block = 1024;                     // 16 waves/block
  const int grid = total_waves / 16;          // 512 blocks
  ball_query_kernel<<<grid, block, 0, stream>>>(x, out, r2);
}